// Round 8
// baseline (338.380 us; speedup 1.0000x reference)
//
#include <hip/hip_runtime.h>

// BahdanauAttnDecoderRNN single-step decode, MI355X — 3 stream-ordered kernels.
// Reference dead code: softmax over size-1 axis => attn_weights == 1.0;
// attn_W/attn_b/scores dead; attn_applied = colsum(encoder_outputs).
// Live work ~178 MB f32 reads (Wout 131 MB dominant); weights are partially
// L3-resident across replays (R4 FETCH=88MB) — use normal cached loads.
// Sync rules learned: NO intra-kernel polling (R4/R5 collapse). Single-shot
// "last arrival wins" atomics are safe (R7). Winner condition uses
// (old & (N-1)) == N-1 with power-of-2 arrivals: immune to ws poison and
// replay accumulation — no counter resets anywhere.
//   K1: colsum partials (64 blks) + gh+gi_emb (768) + attn ones;
//       64th colsum arrival reduces partials -> rn = relu(colsum)
//   K2: gi2 (256 blks x 12 rows, reads rn); 256th arrival -> GRU gates, h_new
//   K3: logits (2048 blks x 16 rows, 4-row ILP) + per-block (m,s) partial;
//       striped 16x128 arrivals; final winner: reduce 2048 partials ->
//       M, L, then in-place log-softmax over d_out (replaces a 4th node)

namespace {
constexpr int H = 1024;
constexpr int V = 32000;
constexpr int S = 2048;
constexpr int NTHR = 256;
constexpr int CS_BLKS = 64;             // colsum chunk blocks (power of 2)
constexpr int CS_ROWS = S / CS_BLKS;    // 32 rows per chunk
constexpr int GRU_BLKS = 768;           // 3072 rows / 4 per block
constexpr int K1_BLKS = CS_BLKS + GRU_BLKS + 1;  // 833
constexpr int K2_BLKS = 256;            // power of 2; 12 gi2 rows each
constexpr int K3_BLKS = 2048;           // power of 2; 16 logit rows each (2000 live)
constexpr int K3_LIVE = 2000;
constexpr int NSTRIPE = 16;             // K3 arrival stripes (128 each)
}

__device__ __forceinline__ float wave_sum(float v) {
#pragma unroll
    for (int off = 32; off > 0; off >>= 1) v += __shfl_xor(v, off, 64);
    return v;
}
__device__ __forceinline__ float wave_max(float v) {
#pragma unroll
    for (int off = 32; off > 0; off >>= 1) v = fmaxf(v, __shfl_xor(v, off, 64));
    return v;
}
__device__ __forceinline__ float dot4(float4 a, float4 b) {
    return a.x * b.x + a.y * b.y + a.z * b.z + a.w * b.w;
}
__device__ __forceinline__ int arrive(int* ctr) {  // returns old value
    return __hip_atomic_fetch_add(ctr, 1, __ATOMIC_ACQ_REL, __HIP_MEMORY_SCOPE_AGENT);
}

// K1: colsum partials + gh & emb-half-of-gi + attn ones; last colsum block
// reduces partials into rn = relu(colsum).
__global__ __launch_bounds__(NTHR) void k1(
    const float* __restrict__ enc, const float* __restrict__ Whh,
    const float* __restrict__ Wih, const float* __restrict__ bih,
    const float* __restrict__ bhh, const float* __restrict__ hin,
    const float* __restrict__ emb, const int* __restrict__ word,
    float* __restrict__ part, float* __restrict__ rn,
    float* __restrict__ gi, float* __restrict__ gh,
    float* __restrict__ out, int* __restrict__ ctrA) {
    const int b = blockIdx.x, t = threadIdx.x;
    __shared__ int win;
    if (b < CS_BLKS) {
        // rows [b*32, b*32+32); thread t owns float4-column t (1KB/row/instr x4)
        const float4* e = (const float4*)enc + (size_t)b * CS_ROWS * (H / 4) + t;
        float4 acc = make_float4(0.f, 0.f, 0.f, 0.f);
#pragma unroll
        for (int r = 0; r < CS_ROWS; ++r) {
            float4 v = e[(size_t)r * (H / 4)];
            acc.x += v.x; acc.y += v.y; acc.z += v.z; acc.w += v.w;
        }
        ((float4*)part)[b * (H / 4) + t] = acc;
        __threadfence();
        __syncthreads();
        if (t == 0) win = ((arrive(ctrA) & (CS_BLKS - 1)) == CS_BLKS - 1);
        __syncthreads();
        if (win) {
            __threadfence();  // acquire: see all partials
            float4 s = make_float4(0.f, 0.f, 0.f, 0.f);
#pragma unroll
            for (int c = 0; c < CS_BLKS; ++c) {
                float4 v = ((const float4*)part)[c * (H / 4) + t];
                s.x += v.x; s.y += v.y; s.z += v.z; s.w += v.w;
            }
            s.x = fmaxf(s.x, 0.f); s.y = fmaxf(s.y, 0.f);
            s.z = fmaxf(s.z, 0.f); s.w = fmaxf(s.w, 0.f);
            ((float4*)rn)[t] = s;
        }
    } else if (b < CS_BLKS + GRU_BLKS) {
        const int lane = t & 63, w = t >> 6;
        const int row = (b - CS_BLKS) * 4 + w;  // < 3072
        const float4* wh = (const float4*)Whh + (size_t)row * (H / 4);
        const float4* xh = (const float4*)hin;
        const float4* wi = (const float4*)Wih + (size_t)row * (2 * H / 4);
        const float4* er = (const float4*)emb + (size_t)word[0] * (H / 4);
        float ah = 0.f, ai = 0.f;
#pragma unroll
        for (int it = 0; it < 4; ++it) {
            const int idx = it * 64 + lane;
            ah += dot4(wh[idx], xh[idx]);
            float4 e4 = er[idx];
            e4.x = fmaxf(e4.x, 0.f); e4.y = fmaxf(e4.y, 0.f);
            e4.z = fmaxf(e4.z, 0.f); e4.w = fmaxf(e4.w, 0.f);
            ai += dot4(wi[idx], e4);
        }
        ah = wave_sum(ah);
        ai = wave_sum(ai);
        if (lane == 0) {
            gh[row] = ah + bhh[row];
            gi[row] = ai + bih[row];  // colsum half lives in gi2
        }
    } else {
        // attn_weights are exactly 1.0 (softmax over size-1 axis)
#pragma unroll
        for (int k = 0; k < S / NTHR; ++k) out[V + H + k * NTHR + t] = 1.0f;
    }
}

// K2: gi2 = Wih[:, H:2H] . rn (256 blocks x 12 rows); last arrival computes
// the GRU gates -> h_new (ws) + hidden-state output (d_out).
__global__ __launch_bounds__(NTHR) void k2(
    const float* __restrict__ Wih, const float* __restrict__ rn,
    const float* __restrict__ gi, const float* __restrict__ gh,
    const float* __restrict__ hin, float* __restrict__ gi2,
    float* __restrict__ hnew, float* __restrict__ out, int* __restrict__ ctrB) {
    __shared__ float4 sh[H / 4];
    __shared__ int win;
    const int t = threadIdx.x, lane = t & 63, w = t >> 6;
    sh[t] = ((const float4*)rn)[t];
    __syncthreads();
#pragma unroll
    for (int i = 0; i < 3; ++i) {
        const int row = blockIdx.x * 12 + w * 3 + i;  // < 3072
        const float4* wr = (const float4*)Wih + (size_t)row * (2 * H / 4) + (H / 4);
        float a = 0.f;
#pragma unroll
        for (int it = 0; it < 4; ++it) {
            const int idx = it * 64 + lane;
            a += dot4(wr[idx], sh[idx]);
        }
        a = wave_sum(a);
        if (lane == 0) gi2[row] = a;
    }
    __threadfence();
    __syncthreads();
    if (t == 0) win = ((arrive(ctrB) & (K2_BLKS - 1)) == K2_BLKS - 1);
    __syncthreads();
    if (!win) return;
    __threadfence();  // acquire: see all gi2
#pragma unroll
    for (int q = 0; q < 4; ++q) {
        const int j = q * NTHR + t;
        const float gr = gi[j] + gi2[j] + gh[j];
        const float gz = gi[H + j] + gi2[H + j] + gh[H + j];
        const float r = 1.f / (1.f + expf(-gr));
        const float z = 1.f / (1.f + expf(-gz));
        const float n = tanhf(gi[2 * H + j] + gi2[2 * H + j] + r * gh[2 * H + j]);
        const float hv = (1.f - z) * n + z * hin[j];
        hnew[j] = hv;
        out[V + j] = hv;  // hidden-state output
    }
}

// K3: logits stream (16 rows/block, explicit 4-row ILP) + per-block (m,s);
// striped arrivals; final winner reduces partials and normalizes in place.
__global__ __launch_bounds__(NTHR) void k3(
    const float* __restrict__ Wout, const float* __restrict__ bout,
    const float* __restrict__ hnew, float* __restrict__ out,
    float* __restrict__ partm, float* __restrict__ parts, int* __restrict__ ctrC) {
    __shared__ float red[8];
    __shared__ int win;
    const int bid = blockIdx.x, t = threadIdx.x, lane = t & 63, w = t >> 6;
    const float4* hn4 = (const float4*)hnew;
    const float4 x0 = hn4[lane], x1 = hn4[64 + lane];
    const float4 x2 = hn4[128 + lane], x3 = hn4[192 + lane];
    if (bid < K3_LIVE) {
        const int r0 = bid * 16 + w * 4;
        const float4* w0 = (const float4*)Wout + (size_t)(r0 + 0) * (H / 4);
        const float4* w1 = (const float4*)Wout + (size_t)(r0 + 1) * (H / 4);
        const float4* w2 = (const float4*)Wout + (size_t)(r0 + 2) * (H / 4);
        const float4* w3 = (const float4*)Wout + (size_t)(r0 + 3) * (H / 4);
        float a0, a1, a2, a3;
        {
            const int i0 = lane, i1 = 64 + lane, i2 = 128 + lane, i3 = 192 + lane;
            a0 = dot4(w0[i0], x0) + dot4(w0[i1], x1) + dot4(w0[i2], x2) + dot4(w0[i3], x3);
            a1 = dot4(w1[i0], x0) + dot4(w1[i1], x1) + dot4(w1[i2], x2) + dot4(w1[i3], x3);
            a2 = dot4(w2[i0], x0) + dot4(w2[i1], x1) + dot4(w2[i2], x2) + dot4(w2[i3], x3);
            a3 = dot4(w3[i0], x0) + dot4(w3[i1], x1) + dot4(w3[i2], x2) + dot4(w3[i3], x3);
        }
        a0 = wave_sum(a0) + bout[r0 + 0];
        a1 = wave_sum(a1) + bout[r0 + 1];
        a2 = wave_sum(a2) + bout[r0 + 2];
        a3 = wave_sum(a3) + bout[r0 + 3];
        if (lane == 0) {
            out[r0 + 0] = a0; out[r0 + 1] = a1;
            out[r0 + 2] = a2; out[r0 + 3] = a3;
        }
        const float m = fmaxf(fmaxf(a0, a1), fmaxf(a2, a3));
        const float s = expf(a0 - m) + expf(a1 - m) + expf(a2 - m) + expf(a3 - m);
        if (lane == 0) { red[w] = m; red[4 + w] = s; }
        __syncthreads();
        if (t == 0) {
            const float M = fmaxf(fmaxf(red[0], red[1]), fmaxf(red[2], red[3]));
            const float ss = red[4] * expf(red[0] - M) + red[5] * expf(red[1] - M) +
                             red[6] * expf(red[2] - M) + red[7] * expf(red[3] - M);
            partm[bid] = M;
            parts[bid] = ss;
        }
    } else {
        if (t == 0) { partm[bid] = -3.4e38f; parts[bid] = 0.f; }
    }
    // striped arrival: 16 stripes x 128; stripe winner arrives level-2.
    __threadfence();
    __syncthreads();
    if (t == 0) {
        win = 0;
        const int o1 = arrive(ctrC + 32 * (bid & (NSTRIPE - 1)));
        if ((o1 & (K3_BLKS / NSTRIPE - 1)) == K3_BLKS / NSTRIPE - 1) {
            __threadfence();
            const int o2 = arrive(ctrC + 32 * NSTRIPE);
            win = ((o2 & (NSTRIPE - 1)) == NSTRIPE - 1);
        }
    }
    __syncthreads();
    if (!win) return;
    __threadfence();  // acquire: all logits + partials visible
    // reduce 2048 partials (fixed order) -> M, L
    float m = -3.4e38f;
#pragma unroll
    for (int i = 0; i < K3_BLKS / NTHR; ++i) m = fmaxf(m, partm[i * NTHR + t]);
    m = wave_max(m);
    if (lane == 0) red[w] = m;
    __syncthreads();
    const float M = fmaxf(fmaxf(red[0], red[1]), fmaxf(red[2], red[3]));
    float s = 0.f;
#pragma unroll
    for (int i = 0; i < K3_BLKS / NTHR; ++i) {
        const int k = i * NTHR + t;
        s += parts[k] * expf(partm[k] - M);
    }
    s = wave_sum(s);
    __syncthreads();
    if (lane == 0) red[w] = s;
    __syncthreads();
    const float L = logf(red[0] + red[1] + red[2] + red[3]);
    // in-place log-softmax over d_out (raw logits are L2/L3-hot)
    for (int i = 0; i < V / NTHR; ++i) {
        const int g = i * NTHR + t;
        out[g] = out[g] - M - L;
    }
}

extern "C" void kernel_launch(void* const* d_in, const int* in_sizes, int n_in,
                              void* d_out, int out_size, void* d_ws, size_t ws_size,
                              hipStream_t stream) {
    const int*   word = (const int*)d_in[0];
    const float* hin  = (const float*)d_in[1];
    const float* enc  = (const float*)d_in[2];
    const float* emb  = (const float*)d_in[3];
    // d_in[4] attn_W, d_in[5] attn_b: dead (softmax over size-1 axis)
    const float* Wih  = (const float*)d_in[6];
    const float* Whh  = (const float*)d_in[7];
    const float* bih  = (const float*)d_in[8];
    const float* bhh  = (const float*)d_in[9];
    const float* Wout = (const float*)d_in[10];
    const float* bout = (const float*)d_in[11];
    float* out = (float*)d_out;

    int* ctr = (int*)d_ws;               // [4096 ints]: A@0, B@32, C stripes@64+32s, C2@576
    int* ctrA = ctr + 0;
    int* ctrB = ctr + 32;
    int* ctrC = ctr + 64;
    float* ws = (float*)d_ws + 4096;     // 16 KB offset
    float* part  = ws;                   // [64*1024]
    float* rn    = part + CS_BLKS * H;   // [1024]
    float* gi    = rn + H;               // [3072]
    float* gi2   = gi + 3 * H;           // [3072]
    float* gh    = gi2 + 3 * H;          // [3072]
    float* hnew  = gh + 3 * H;           // [1024]
    float* partm = hnew + H;             // [2048]
    float* parts = partm + K3_BLKS;      // [2048]

    k1<<<K1_BLKS, NTHR, 0, stream>>>(enc, Whh, Wih, bih, bhh, hin, emb, word,
                                     part, rn, gi, gh, out, ctrA);
    k2<<<K2_BLKS, NTHR, 0, stream>>>(Wih, rn, gi, gh, hin, gi2, hnew, out, ctrB);
    k3<<<K3_BLKS, NTHR, 0, stream>>>(Wout, bout, hnew, out, partm, parts, ctrC);
}

// Round 9
// 47.917 us; speedup vs baseline: 7.0619x; 7.0619x over previous
//
#include <hip/hip_runtime.h>

// BahdanauAttnDecoderRNN single-step decode, MI355X — 4 stream-ordered kernels.
// Reference dead code: softmax over size-1 axis => attn_weights == 1.0;
// attn_W/attn_b/scores dead; attn_applied = colsum(encoder_outputs).
// Live work ~178 MB f32 reads (Wout 131 MB dominant) => ~28 us HBM roofline.
// Sync lessons (hard-won):
//   R4 coop grid.sync: 441 us. R5 polling DAG: 486 us. R8 2048-block fan-in
//   winner: 420 us + visibility failure (absmax 0.0625). NO intra-kernel
//   cross-block dependencies at scale; fan-in <= 256 only (R7 worked).
// This round: R6 structure exactly (best: 60.7 us, zero atomics), single
// change: k_logits 2000x16 -> 1000x32 rows (8 rows/wave) to halve per-block
// overhead (gates-prologue L3 re-reads 80->40 MB, launches, barriers).
//   D1: colsum partials (32 chunks) + gh + emb-half gi + attn ones
//   D2: per-block partial-reduce + colsum-half gi2
//   D3: gates redundant per block + 32-row logits matvec + per-block (m,s)
//   D4: fixed-order reduce of 1000 partials + in-place log-softmax

namespace {
constexpr int H = 1024;
constexpr int V = 32000;
constexpr int S = 2048;
constexpr int NTHR = 256;
constexpr int CS_BLKS = 32;             // colsum chunks
constexpr int CS_ROWS = S / CS_BLKS;    // 64 rows per chunk
constexpr int GRU_BLKS = 768;           // 3072 rows / 4 per block
constexpr int D1_BLKS = CS_BLKS + GRU_BLKS + 1;  // 801
constexpr int D2_BLKS = 192;            // 16 gi2 rows each
constexpr int D3_BLKS = 1000;           // 32 logits rows each (8 per wave)
constexpr int RPW = 8;                  // rows per wave in D3
constexpr int D4_BLKS = V / NTHR;       // 125
}

__device__ __forceinline__ float wave_sum(float v) {
#pragma unroll
    for (int off = 32; off > 0; off >>= 1) v += __shfl_xor(v, off, 64);
    return v;
}
__device__ __forceinline__ float wave_max(float v) {
#pragma unroll
    for (int off = 32; off > 0; off >>= 1) v = fmaxf(v, __shfl_xor(v, off, 64));
    return v;
}
__device__ __forceinline__ float dot4(float4 a, float4 b) {
    return a.x * b.x + a.y * b.y + a.z * b.z + a.w * b.w;
}

// D1: colsum partials + gh & emb-half of gi + attn ones.
__global__ __launch_bounds__(NTHR) void k_front(
    const float* __restrict__ enc, const float* __restrict__ Whh,
    const float* __restrict__ Wih, const float* __restrict__ bih,
    const float* __restrict__ bhh, const float* __restrict__ hin,
    const float* __restrict__ emb, const int* __restrict__ word,
    float* __restrict__ part, float* __restrict__ gi, float* __restrict__ gh,
    float* __restrict__ out) {
    const int b = blockIdx.x, t = threadIdx.x;
    if (b < CS_BLKS) {
        // rows [b*64, b*64+64); thread t owns float4-column t
        const float4* e = (const float4*)enc + (size_t)b * CS_ROWS * (H / 4) + t;
        float4 acc = make_float4(0.f, 0.f, 0.f, 0.f);
#pragma unroll
        for (int r = 0; r < CS_ROWS; ++r) {
            float4 v = e[(size_t)r * (H / 4)];
            acc.x += v.x; acc.y += v.y; acc.z += v.z; acc.w += v.w;
        }
        ((float4*)part)[b * (H / 4) + t] = acc;
    } else if (b < CS_BLKS + GRU_BLKS) {
        const int lane = t & 63, w = t >> 6;
        const int row = (b - CS_BLKS) * 4 + w;  // < 3072
        const float4* wh = (const float4*)Whh + (size_t)row * (H / 4);
        const float4* xh = (const float4*)hin;
        const float4* wi = (const float4*)Wih + (size_t)row * (2 * H / 4);
        const float4* er = (const float4*)emb + (size_t)word[0] * (H / 4);
        float ah = 0.f, ai = 0.f;
#pragma unroll
        for (int it = 0; it < 4; ++it) {
            const int idx = it * 64 + lane;
            ah += dot4(wh[idx], xh[idx]);
            float4 e4 = er[idx];
            e4.x = fmaxf(e4.x, 0.f); e4.y = fmaxf(e4.y, 0.f);
            e4.z = fmaxf(e4.z, 0.f); e4.w = fmaxf(e4.w, 0.f);
            ai += dot4(wi[idx], e4);
        }
        ah = wave_sum(ah);
        ai = wave_sum(ai);
        if (lane == 0) {
            gh[row] = ah + bhh[row];
            gi[row] = ai + bih[row];  // colsum half lives in gi2
        }
    } else {
        // attn_weights are exactly 1.0 (softmax over size-1 axis)
#pragma unroll
        for (int k = 0; k < S / NTHR; ++k) out[V + H + k * NTHR + t] = 1.0f;
    }
}

// D2: per-block redundant reduce of 32 colsum partials -> relu -> LDS;
// then 16 rows of gi2 = Wih[:, H:2H] . rn.
__global__ __launch_bounds__(NTHR) void k_gi2(
    const float* __restrict__ Wih, const float* __restrict__ part,
    float* __restrict__ gi2) {
    __shared__ float4 rn[H / 4];
    const int t = threadIdx.x, lane = t & 63, w = t >> 6;
    float4 acc = make_float4(0.f, 0.f, 0.f, 0.f);
#pragma unroll
    for (int c = 0; c < CS_BLKS; ++c) {
        float4 v = ((const float4*)part)[c * (H / 4) + t];
        acc.x += v.x; acc.y += v.y; acc.z += v.z; acc.w += v.w;
    }
    acc.x = fmaxf(acc.x, 0.f); acc.y = fmaxf(acc.y, 0.f);
    acc.z = fmaxf(acc.z, 0.f); acc.w = fmaxf(acc.w, 0.f);
    rn[t] = acc;
    __syncthreads();
#pragma unroll
    for (int i = 0; i < 4; ++i) {
        const int row = blockIdx.x * 16 + w * 4 + i;  // < 3072
        const float4* wr = (const float4*)Wih + (size_t)row * (2 * H / 4) + (H / 4);
        float a = 0.f;
#pragma unroll
        for (int it = 0; it < 4; ++it) {
            const int idx = it * 64 + lane;
            a += dot4(wr[idx], rn[idx]);
        }
        a = wave_sum(a);
        if (lane == 0) gi2[row] = a;
    }
}

// D3: gates redundant per block -> h_new in LDS -> 32-row Wout matvec
// (8 rows/wave, register batch) -> raw logits + per-block (m,s) partial.
__global__ __launch_bounds__(NTHR) void k_logits(
    const float* __restrict__ gi, const float* __restrict__ gi2,
    const float* __restrict__ gh, const float* __restrict__ hin,
    const float* __restrict__ Wout, const float* __restrict__ bout,
    float* __restrict__ out, float* __restrict__ partm, float* __restrict__ parts) {
    __shared__ float hnew[H];
    __shared__ float bm[4], bs[4];
    const int t = threadIdx.x, lane = t & 63, w = t >> 6;
#pragma unroll
    for (int q = 0; q < 4; ++q) {
        const int j = q * NTHR + t;
        const float gr = gi[j] + gi2[j] + gh[j];
        const float gz = gi[H + j] + gi2[H + j] + gh[H + j];
        const float r = 1.f / (1.f + expf(-gr));
        const float z = 1.f / (1.f + expf(-gz));
        const float n = tanhf(gi[2 * H + j] + gi2[2 * H + j] + r * gh[2 * H + j]);
        const float hv = (1.f - z) * n + z * hin[j];
        hnew[j] = hv;
        if (blockIdx.x == 0) out[V + j] = hv;  // hidden-state output
    }
    __syncthreads();
    const float4* hn4 = (const float4*)hnew;
    const float4 x0 = hn4[lane], x1 = hn4[64 + lane];
    const float4 x2 = hn4[128 + lane], x3 = hn4[192 + lane];
    float a[RPW];
#pragma unroll 2
    for (int i = 0; i < RPW; ++i) {
        const int row = blockIdx.x * 32 + w * RPW + i;  // < 32000
        const float4* wr = (const float4*)Wout + (size_t)row * (H / 4);
        float v = dot4(wr[lane], x0) + dot4(wr[64 + lane], x1) +
                  dot4(wr[128 + lane], x2) + dot4(wr[192 + lane], x3);
        a[i] = wave_sum(v) + bout[row];  // identical on all lanes
        if (lane == 0) out[row] = a[i];  // raw logit
    }
    float m = a[0];
#pragma unroll
    for (int i = 1; i < RPW; ++i) m = fmaxf(m, a[i]);
    float s = 0.f;
#pragma unroll
    for (int i = 0; i < RPW; ++i) s += expf(a[i] - m);
    if (lane == 0) { bm[w] = m; bs[w] = s; }
    __syncthreads();
    if (t == 0) {
        const float M = fmaxf(fmaxf(bm[0], bm[1]), fmaxf(bm[2], bm[3]));
        const float ss = bs[0] * expf(bm[0] - M) + bs[1] * expf(bm[1] - M) +
                         bs[2] * expf(bm[2] - M) + bs[3] * expf(bm[3] - M);
        partm[blockIdx.x] = M;
        parts[blockIdx.x] = ss;
    }
}

// D4: redundant fixed-order reduce of 1000 partials + in-place log-softmax.
__global__ __launch_bounds__(NTHR) void k_final(
    const float* __restrict__ partm, const float* __restrict__ parts,
    float* __restrict__ out) {
    __shared__ float ms[4], ss[4];
    const int t = threadIdx.x, lane = t & 63, w = t >> 6;
    float m = -3.4e38f;
    for (int k = t; k < D3_BLKS; k += NTHR) m = fmaxf(m, partm[k]);
    m = wave_max(m);
    if (lane == 0) ms[w] = m;
    __syncthreads();
    const float M = fmaxf(fmaxf(ms[0], ms[1]), fmaxf(ms[2], ms[3]));
    float s = 0.f;
    for (int k = t; k < D3_BLKS; k += NTHR) s += parts[k] * expf(partm[k] - M);
    s = wave_sum(s);
    if (lane == 0) ss[w] = s;
    __syncthreads();
    const float L = logf(ss[0] + ss[1] + ss[2] + ss[3]);
    const int g = blockIdx.x * NTHR + t;  // 125*256 = 32000
    out[g] = out[g] - M - L;
}

extern "C" void kernel_launch(void* const* d_in, const int* in_sizes, int n_in,
                              void* d_out, int out_size, void* d_ws, size_t ws_size,
                              hipStream_t stream) {
    const int*   word = (const int*)d_in[0];
    const float* hin  = (const float*)d_in[1];
    const float* enc  = (const float*)d_in[2];
    const float* emb  = (const float*)d_in[3];
    // d_in[4] attn_W, d_in[5] attn_b: dead (softmax over size-1 axis)
    const float* Wih  = (const float*)d_in[6];
    const float* Whh  = (const float*)d_in[7];
    const float* bih  = (const float*)d_in[8];
    const float* bhh  = (const float*)d_in[9];
    const float* Wout = (const float*)d_in[10];
    const float* bout = (const float*)d_in[11];
    float* out = (float*)d_out;
    float* ws  = (float*)d_ws;

    float* part  = ws;                  // [32*1024]
    float* gi    = part + CS_BLKS * H;  // [3072]
    float* gi2   = gi + 3 * H;          // [3072]
    float* gh    = gi2 + 3 * H;         // [3072]
    float* partm = gh + 3 * H;          // [1000]
    float* parts = partm + D3_BLKS;     // [1000]

    k_front<<<D1_BLKS, NTHR, 0, stream>>>(enc, Whh, Wih, bih, bhh, hin, emb, word,
                                          part, gi, gh, out);
    k_gi2<<<D2_BLKS, NTHR, 0, stream>>>(Wih, part, gi2);
    k_logits<<<D3_BLKS, NTHR, 0, stream>>>(gi, gi2, gh, hin, Wout, bout, out,
                                           partm, parts);
    k_final<<<D4_BLKS, NTHR, 0, stream>>>(partm, parts, out);
}